// Round 3
// baseline (240.908 us; speedup 1.0000x reference)
//
#include <hip/hip_runtime.h>
#include <stdint.h>

#define D_DIM 4096
#define N_ROWS 8192

typedef __attribute__((ext_vector_type(8))) short bfrag8;
typedef __attribute__((ext_vector_type(4))) float facc4;
typedef unsigned long long u64;

__device__ __forceinline__ uint32_t pack_bf16x2(float lo, float hi) {
    union { float f; uint32_t u; } a, b;
    a.f = lo; b.f = hi;
    return (b.u & 0xFFFF0000u) | (a.u >> 16);   // truncate-to-bf16
}

// ---------------------------------------------------------------------------
// Kernel 0: build fragment-ordered bf16 B-image from A (fp32 [128][4096]).
// Frag-block fb = chunk*16 + t*2 + ks  (chunk = 64-K slab, t = 16-col n-tile,
// ks = 32-K MFMA step). Slot = fb*64 + lane, 16 B each:
//   holds A[16t + (lane&15)][chunk*64 + ks*32 + (lane>>4)*8 + j], j=0..7 (bf16)
// So the GEMM's B-frag load is ONE lane-contiguous global_load_dwordx4.
// ---------------------------------------------------------------------------
__global__ void __launch_bounds__(256)
prep_A(const float* __restrict__ A, uint32_t* __restrict__ Bimg) {
    const int S = blockIdx.x * 256 + threadIdx.x;  // 0..65535
    const int chunk = S >> 10;
    const int rest  = S & 1023;
    const int tks   = rest >> 6;        // 0..15
    const int lane  = rest & 63;
    const int t  = tks >> 1;
    const int ks = tks & 1;
    const int c  = lane & 15;
    const int q  = lane >> 4;
    const float* src = A + (size_t)(16 * t + c) * D_DIM + chunk * 64 + ks * 32 + q * 8;
    float4 f0 = *(const float4*)(src);
    float4 f1 = *(const float4*)(src + 4);
    uint4 o;
    o.x = pack_bf16x2(f0.x, f0.y);
    o.y = pack_bf16x2(f0.z, f0.w);
    o.z = pack_bf16x2(f1.x, f1.y);
    o.w = pack_bf16x2(f1.z, f1.w);
    *(uint4*)(Bimg + (size_t)S * 4) = o;
}

// ---------------------------------------------------------------------------
// Kernel 1: barrier-free direct-register GEMM. One wave = 16 rows x 128 cols
// x (64/S) 64-K chunks. No LDS, no __syncthreads: B-frags stream from the
// frag-ordered image (L2-hot), A-frags load fp32 from L and pack in-register.
// Compiler can overlap next-chunk loads with MFMAs (no vmcnt(0) drains).
// ---------------------------------------------------------------------------
__global__ void __launch_bounds__(256, 3)
gemm_direct(const float* __restrict__ L, const uint32_t* __restrict__ Bimg,
            float* __restrict__ partials, int kpb) {
    const int tid  = threadIdx.x;
    const int lane = tid & 63;
    const int gw   = blockIdx.x * 4 + (tid >> 6);   // global wave id
    const int split = gw >> 9;                      // waves-per-split is always 512
    const int mwave = gw & 511;                     // 16-row group
    const int c = lane & 15;
    const int q = lane >> 4;

    const float* lrow = L + (size_t)(16 * mwave + c) * D_DIM;  // per-lane row

    facc4 acc[8];
#pragma unroll
    for (int t = 0; t < 8; t++) acc[t] = (facc4){0.f, 0.f, 0.f, 0.f};

    const int k0 = split * kpb;
#pragma unroll 2
    for (int k = k0; k < k0 + kpb; k++) {
        const int kc = k * 64;
        // A-frags: 2 ks-steps, 32 B contiguous per lane each, packed to bf16
        bfrag8 a[2];
#pragma unroll
        for (int ks = 0; ks < 2; ks++) {
            const float* p = lrow + kc + ks * 32 + q * 8;
            float4 f0 = *(const float4*)(p);
            float4 f1 = *(const float4*)(p + 4);
            uint4 u;
            u.x = pack_bf16x2(f0.x, f0.y);
            u.y = pack_bf16x2(f0.z, f0.w);
            u.z = pack_bf16x2(f1.x, f1.y);
            u.w = pack_bf16x2(f1.z, f1.w);
            a[ks] = *(bfrag8*)&u;
        }
        // B-frags: 16 coalesced dwordx4 from the frag image; MFMA as they land
        const uint32_t* bbase = Bimg + ((size_t)k * 16) * 256 + lane * 4;
#pragma unroll
        for (int t = 0; t < 8; t++) {
#pragma unroll
            for (int ks = 0; ks < 2; ks++) {
                bfrag8 b = *(const bfrag8*)(bbase + (t * 2 + ks) * 256);
                acc[t] = __builtin_amdgcn_mfma_f32_16x16x32_bf16(a[ks], b, acc[t], 0, 0, 0);
            }
        }
    }

    // C/D layout (m89/m91-verified): m-row = 4q + r, n-col = 16t + c
    float* P = partials + (size_t)split * N_ROWS * 128 + (size_t)(16 * mwave) * 128;
#pragma unroll
    for (int t = 0; t < 8; t++)
#pragma unroll
        for (int r = 0; r < 4; r++)
            P[(4 * q + r) * 128 + 16 * t + c] = acc[t][r];
}

// ---------------------------------------------------------------------------
// Kernel 2: reduce S partial planes, sign -> 128-bit key -> 64-bit fold.
// One wave per row; lane covers cols (lane, lane+64).
// ---------------------------------------------------------------------------
__global__ void __launch_bounds__(256)
reduce_pack(const float* __restrict__ partials, u64* __restrict__ folded, int S) {
    const int row  = blockIdx.x * 4 + (threadIdx.x >> 6);
    const int lane = threadIdx.x & 63;
    float s0 = 0.f, s1 = 0.f;
    for (int s = 0; s < S; s++) {
        const float* P = partials + ((size_t)s * N_ROWS * 128) + (size_t)row * 128;
        s0 += P[lane];
        s1 += P[lane + 64];
    }
    u64 b0 = __ballot(s0 > 0.0f);
    u64 b1 = __ballot(s1 > 0.0f);
    if (lane == 0) folded[row] = b0 ^ b1;
}

// ---------------------------------------------------------------------------
// Kernel 3: ordered duplicate count, LDS-staged keys. 512 blocks x 256 thr
// (2 blocks/CU); wave g handles rows {g, g+2048, g+4096, g+6144}.
// ---------------------------------------------------------------------------
__global__ void __launch_bounds__(256)
count_rows(const u64* __restrict__ folded, float* __restrict__ out) {
    __shared__ u64 K[N_ROWS];
    const int tid = threadIdx.x;
    for (int i = tid; i < N_ROWS / 2; i += 256)
        ((uint4*)K)[i] = ((const uint4*)folded)[i];
    __syncthreads();

    const int g    = blockIdx.x * 4 + (tid >> 6);   // 0..2047
    const int lane = tid & 63;
    int rows[4];
    u64 my[4];
    int cnt[4] = {0, 0, 0, 0};
#pragma unroll
    for (int r = 0; r < 4; r++) {
        rows[r] = g + 2048 * r;
        my[r] = K[rows[r]];
    }
    const int maxrow = rows[3];
    for (int j = lane; j <= maxrow; j += 64) {
        u64 k = K[j];
#pragma unroll
        for (int r = 0; r < 4; r++)
            cnt[r] += (int)((j <= rows[r]) & (k == my[r]));
    }
#pragma unroll
    for (int r = 0; r < 4; r++) {
        int v = cnt[r];
#pragma unroll
        for (int o = 32; o; o >>= 1) v += __shfl_xor(v, o, 64);
        if (lane == 0) out[rows[r]] = rsqrtf((float)v);
    }
}

extern "C" void kernel_launch(void* const* d_in, const int* in_sizes, int n_in,
                              void* d_out, int out_size, void* d_ws, size_t ws_size,
                              hipStream_t stream) {
    const float* latent = (const float*)d_in[0];   // [128,64,4096] fp32
    const float* A      = (const float*)d_in[1];   // [128,4096] fp32
    float* out          = (float*)d_out;           // [8192] fp32

    uint32_t* Bimg = (uint32_t*)d_ws;                                   // 1 MB
    u64* folded = (u64*)((char*)d_ws + (1 << 20));                      // 64 KB
    float* partials = (float*)((char*)d_ws + (1 << 20) + (1 << 16));    // S * 4 MB

    const size_t base = (1 << 20) + (1 << 16);
    const size_t per_split = (size_t)N_ROWS * 128 * sizeof(float);      // 4 MB
    int S = 1;
    if (ws_size >= base + 8 * per_split)      S = 8;
    else if (ws_size >= base + 4 * per_split) S = 4;
    else if (ws_size >= base + 2 * per_split) S = 2;

    prep_A<<<256, 256, 0, stream>>>(A, Bimg);
    gemm_direct<<<128 * S, 256, 0, stream>>>(latent, Bimg, partials, 64 / S);
    reduce_pack<<<2048, 256, 0, stream>>>(partials, folded, S);
    count_rows<<<512, 256, 0, stream>>>(folded, out);
}